// Round 7
// baseline (641.800 us; speedup 1.0000x reference)
//
#include <hip/hip_runtime.h>
#include <hip/hip_bf16.h>
#include <cstdint>
#include <cstddef>

#define NN 100000
#define NE 1600000
#define FIN 128
#define HD 64
#define NC 40
#define NTILE (NN / 16)                      // 6250 MFMA row-tiles

#define SCAN_CHUNK 2048
#define NB_SCAN ((NN + SCAN_CHUNK - 1) / SCAN_CHUNK)   // 49

#define CB 2048                              // node cols per count block
#define NCB ((NN + CB - 1) / CB)             // 49

typedef unsigned short u16;
typedef unsigned int u32;
typedef __attribute__((ext_vector_type(8))) short short8v;
typedef __attribute__((ext_vector_type(4))) float accf4;

__device__ __forceinline__ float u2lo(u32 u) { return __uint_as_float(u << 16); }
__device__ __forceinline__ float u2hi(u32 u) { return __uint_as_float(u & 0xFFFF0000u); }
__device__ __forceinline__ u16 f2b(float f) {            // RNE f32->bf16
    u32 u = __float_as_uint(f);
    return (u16)((u + 0x7FFFu + ((u >> 16) & 1u)) >> 16);
}

// ---------------- setup kernels ----------------

// LDS-histogram count: each block owns node range [base, base+CB), scans all
// edge cols; zero global atomics. packed[c] = count<<20 | Q6.14 weight-sum.
// pos[e] = edge's slot position within its target node.
__launch_bounds__(1024)
__global__ void k_count2(const int* __restrict__ ei, const float* __restrict__ ew,
                         u32* __restrict__ packed, u16* __restrict__ pos) {
    __shared__ u32 hcnt[CB];
    int tid = threadIdx.x;
    int base = blockIdx.x * CB;
    for (int i = tid; i < CB; i += 1024) hcnt[i] = 0;
    __syncthreads();
    const int4* cols = (const int4*)(ei + NE);
    for (int i = tid; i < NE / 4; i += 1024) {
        int4 c4 = cols[i];
        int e = i * 4;
        u32 cc;
        cc = (u32)(c4.x - base);
        if (cc < CB) { u32 fx = __float2uint_rn(ew[e+0] * 16384.f);
                       u32 old = atomicAdd(&hcnt[cc], (1u << 20) | fx); pos[e+0] = (u16)(old >> 20); }
        cc = (u32)(c4.y - base);
        if (cc < CB) { u32 fx = __float2uint_rn(ew[e+1] * 16384.f);
                       u32 old = atomicAdd(&hcnt[cc], (1u << 20) | fx); pos[e+1] = (u16)(old >> 20); }
        cc = (u32)(c4.z - base);
        if (cc < CB) { u32 fx = __float2uint_rn(ew[e+2] * 16384.f);
                       u32 old = atomicAdd(&hcnt[cc], (1u << 20) | fx); pos[e+2] = (u16)(old >> 20); }
        cc = (u32)(c4.w - base);
        if (cc < CB) { u32 fx = __float2uint_rn(ew[e+3] * 16384.f);
                       u32 old = atomicAdd(&hcnt[cc], (1u << 20) | fx); pos[e+3] = (u16)(old >> 20); }
    }
    __syncthreads();
    for (int i = tid; i < CB; i += 1024)
        if (base + i < NN) packed[base + i] = hcnt[i];
}

// ---- two-level exclusive scan over counts (packed hi-12) -> off; also emits dinv ----

__launch_bounds__(256)
__global__ void k_scan_local(const u32* __restrict__ packed, int* __restrict__ off,
                             int* __restrict__ bsum, float* __restrict__ dinv) {
    __shared__ int wtot[4];
    int tid = threadIdx.x, lane = tid & 63, wid = tid >> 6;
    int base = blockIdx.x * SCAN_CHUNK + tid * 8;
    int v[8];
    int s = 0;
    #pragma unroll
    for (int i = 0; i < 8; i++) {
        if (base + i < NN) {
            u32 p = packed[base + i];
            v[i] = (int)(p >> 20);
            float deg = 1.0f + (float)(p & 0xFFFFFu) * (1.0f / 16384.0f);
            dinv[base + i] = rsqrtf(deg);
        } else v[i] = 0;
    }
    #pragma unroll
    for (int i = 0; i < 8; i++) s += v[i];
    int inc = s;
    #pragma unroll
    for (int d = 1; d < 64; d <<= 1) {
        int t = __shfl_up(inc, d);
        if (lane >= d) inc += t;
    }
    if (lane == 63) wtot[wid] = inc;
    __syncthreads();
    int wof = 0;
    #pragma unroll
    for (int k = 0; k < 4; k++) if (k < wid) wof += wtot[k];
    int run = wof + inc - s;
    #pragma unroll
    for (int i = 0; i < 8; i++) {
        if (base + i < NN) off[base + i] = run;
        run += v[i];
    }
    if (tid == 255) bsum[blockIdx.x] = wof + inc;
}

__global__ void k_scan_bsum(int* __restrict__ bsum, int* __restrict__ off) {
    int lane = threadIdx.x;
    int v = (lane < NB_SCAN) ? bsum[lane] : 0;
    int inc = v;
    #pragma unroll
    for (int d = 1; d < 64; d <<= 1) {
        int t = __shfl_up(inc, d);
        if (lane >= d) inc += t;
    }
    if (lane < NB_SCAN) bsum[lane] = inc - v;
    if (lane == 63) off[NN] = inc;
}

__launch_bounds__(256)
__global__ void k_scan_add(int* __restrict__ off, const int* __restrict__ bsum) {
    int carry = bsum[blockIdx.x];
    int base = blockIdx.x * SCAN_CHUNK + threadIdx.x * 8;
    if (base + 7 < NN) {
        int4* p = (int4*)(off + base);
        int4 a = p[0], b = p[1];
        a.x+=carry; a.y+=carry; a.z+=carry; a.w+=carry;
        b.x+=carry; b.y+=carry; b.z+=carry; b.w+=carry;
        p[0] = a; p[1] = b;
    } else {
        for (int i = 0; i < 8 && base + i < NN; i++) off[base + i] += carry;
    }
}

// atomic-free fill: slot = off[col] + pos[e]; one fused 8B store
__global__ void k_fill(const int* __restrict__ ei, const float* __restrict__ ew,
                       const float* __restrict__ dinv, const int* __restrict__ off,
                       const u16* __restrict__ pos, uint2* __restrict__ csr) {
    int e = blockIdx.x * 256 + threadIdx.x;
    if (e < NE) {
        int r = ei[e], c = ei[NE + e];
        float nv = dinv[r] * ew[e] * dinv[c];
        int slot = off[c] + (int)pos[e];
        csr[slot] = make_uint2((u32)r, __float_as_uint(nv));
    }
}

// ---------------- dense layers (MFMA bf16) ----------------

// h(bf16) = relu(x @ W + b): [NN,128]@[128,64]; one wave per 16-node tile
__launch_bounds__(256)
__global__ void k_lin1(const float* __restrict__ x, const float* __restrict__ W,
                       const float* __restrict__ b, u16* __restrict__ out) {
    int lane = threadIdx.x & 63;
    int tile = blockIdx.x * 4 + (threadIdx.x >> 6);
    if (tile >= NTILE) return;
    int row = lane & 15;                   // A-row (node) / B-col (feature)
    int kg  = lane >> 4;                   // k-group
    short8v bW[4][4];                      // [ktile][coltile]
    #pragma unroll
    for (int kt = 0; kt < 4; kt++)
        #pragma unroll
        for (int ct = 0; ct < 4; ct++)
            #pragma unroll
            for (int j = 0; j < 8; j++)
                bW[kt][ct][j] = (short)f2b(W[(kt*32 + kg*8 + j) * HD + ct*16 + row]);
    int node0 = tile * 16;
    const float* xr = x + (size_t)(node0 + row) * FIN + kg * 8;
    float4 xa[4][2];
    #pragma unroll
    for (int kt = 0; kt < 4; kt++) {
        xa[kt][0] = *(const float4*)(xr + kt*32);
        xa[kt][1] = *(const float4*)(xr + kt*32 + 4);
    }
    short8v af[4];
    #pragma unroll
    for (int kt = 0; kt < 4; kt++) {
        af[kt][0] = (short)f2b(xa[kt][0].x); af[kt][1] = (short)f2b(xa[kt][0].y);
        af[kt][2] = (short)f2b(xa[kt][0].z); af[kt][3] = (short)f2b(xa[kt][0].w);
        af[kt][4] = (short)f2b(xa[kt][1].x); af[kt][5] = (short)f2b(xa[kt][1].y);
        af[kt][6] = (short)f2b(xa[kt][1].z); af[kt][7] = (short)f2b(xa[kt][1].w);
    }
    accf4 acc[4] = {};
    #pragma unroll
    for (int kt = 0; kt < 4; kt++)
        #pragma unroll
        for (int ct = 0; ct < 4; ct++)
            acc[ct] = __builtin_amdgcn_mfma_f32_16x16x32_bf16(af[kt], bW[kt][ct], acc[ct], 0, 0, 0);
    #pragma unroll
    for (int ct = 0; ct < 4; ct++) {
        float bias = b[ct*16 + row];
        #pragma unroll
        for (int r = 0; r < 4; r++) {
            float v = fmaxf(acc[ct][r] + bias, 0.f);
            out[(size_t)(node0 + kg*4 + r) * HD + ct*16 + row] = f2b(v);
        }
    }
}

// out(bf16) = A(bf16) @ W (no bias): [NN,64]@[64,64]
__launch_bounds__(256)
__global__ void k_mm64(const u16* __restrict__ A, const float* __restrict__ W,
                       u16* __restrict__ out) {
    int lane = threadIdx.x & 63;
    int tile = blockIdx.x * 4 + (threadIdx.x >> 6);
    if (tile >= NTILE) return;
    int row = lane & 15;
    int kg  = lane >> 4;
    short8v bW[2][4];
    #pragma unroll
    for (int kt = 0; kt < 2; kt++)
        #pragma unroll
        for (int ct = 0; ct < 4; ct++)
            #pragma unroll
            for (int j = 0; j < 8; j++)
                bW[kt][ct][j] = (short)f2b(W[(kt*32 + kg*8 + j) * HD + ct*16 + row]);
    int node0 = tile * 16;
    const u16* ar = A + (size_t)(node0 + row) * HD + kg * 8;
    short8v af0 = *(const short8v*)(ar);
    short8v af1 = *(const short8v*)(ar + 32);
    accf4 acc[4] = {};
    #pragma unroll
    for (int ct = 0; ct < 4; ct++) {
        acc[ct] = __builtin_amdgcn_mfma_f32_16x16x32_bf16(af0, bW[0][ct], acc[ct], 0, 0, 0);
        acc[ct] = __builtin_amdgcn_mfma_f32_16x16x32_bf16(af1, bW[1][ct], acc[ct], 0, 0, 0);
    }
    #pragma unroll
    for (int ct = 0; ct < 4; ct++)
        #pragma unroll
        for (int r = 0; r < 4; r++)
            out[(size_t)(node0 + kg*4 + r) * HD + ct*16 + row] = f2b(acc[ct][r]);
}

// out(bf16) = relu(Ahat @ Bm + bias): 4 nodes/wave, 16 lanes/row, csr prefetch
__launch_bounds__(256)
__global__ void k_agg(const u32* __restrict__ Bm2, const int* __restrict__ off,
                      const uint2* __restrict__ csr, const float* __restrict__ dinv,
                      const float* __restrict__ bias, uint2* __restrict__ outp) {
    int lane = threadIdx.x & 63;
    int wave = threadIdx.x >> 6;
    int q    = lane >> 4;
    int fp   = lane & 15;
    int node = blockIdx.x * 16 + wave * 4 + q;
    int s = off[node], e = off[node + 1];
    int deg = e - s;
    float di = dinv[node];
    float sc = di * di;
    uint2 sw = *(const uint2*)(Bm2 + (size_t)node * 32 + fp * 2);
    float4 acc;
    acc.x = sc * u2lo(sw.x); acc.y = sc * u2hi(sw.x);
    acc.z = sc * u2lo(sw.y); acc.w = sc * u2hi(sw.y);
    uint2 c0 = csr[s+0], c1 = csr[s+1], c2 = csr[s+2], c3 = csr[s+3];
    for (int j = 0; __any(j < deg); j += 4) {
        // prefetch next chunk (csr +128 pad keeps over-reads in-bounds)
        uint2 n0 = csr[s+j+4], n1 = csr[s+j+5], n2 = csr[s+j+6], n3 = csr[s+j+7];
        bool a0 = (j+0) < deg; u32 r0 = a0 ? c0.x : (u32)node; float w0 = a0 ? __uint_as_float(c0.y) : 0.f;
        bool a1 = (j+1) < deg; u32 r1 = a1 ? c1.x : (u32)node; float w1 = a1 ? __uint_as_float(c1.y) : 0.f;
        bool a2 = (j+2) < deg; u32 r2 = a2 ? c2.x : (u32)node; float w2 = a2 ? __uint_as_float(c2.y) : 0.f;
        bool a3 = (j+3) < deg; u32 r3 = a3 ? c3.x : (u32)node; float w3 = a3 ? __uint_as_float(c3.y) : 0.f;
        uint2 g0 = *(const uint2*)(Bm2 + (size_t)r0 * 32 + fp * 2);
        uint2 g1 = *(const uint2*)(Bm2 + (size_t)r1 * 32 + fp * 2);
        uint2 g2 = *(const uint2*)(Bm2 + (size_t)r2 * 32 + fp * 2);
        uint2 g3 = *(const uint2*)(Bm2 + (size_t)r3 * 32 + fp * 2);
        acc.x += w0 * u2lo(g0.x) + w1 * u2lo(g1.x);
        acc.y += w0 * u2hi(g0.x) + w1 * u2hi(g1.x);
        acc.z += w0 * u2lo(g0.y) + w1 * u2lo(g1.y);
        acc.w += w0 * u2hi(g0.y) + w1 * u2hi(g1.y);
        acc.x += w2 * u2lo(g2.x) + w3 * u2lo(g3.x);
        acc.y += w2 * u2hi(g2.x) + w3 * u2hi(g3.x);
        acc.z += w2 * u2lo(g2.y) + w3 * u2lo(g3.y);
        acc.w += w2 * u2hi(g2.y) + w3 * u2hi(g3.y);
        c0 = n0; c1 = n1; c2 = n2; c3 = n3;
    }
    float4 bv = *(const float4*)(bias + fp * 4);
    uint2 ov;
    ov.x = (u32)f2b(fmaxf(acc.x + bv.x, 0.f)) | ((u32)f2b(fmaxf(acc.y + bv.y, 0.f)) << 16);
    ov.y = (u32)f2b(fmaxf(acc.z + bv.z, 0.f)) | ((u32)f2b(fmaxf(acc.w + bv.w, 0.f)) << 16);
    outp[(size_t)node * 16 + fp] = ov;
}

// logits = H(bf16) @ Wo + bo ; out = log_softmax (MFMA, 3 col-tiles, zero-padded)
__launch_bounds__(256)
__global__ void k_out(const u16* __restrict__ Hm, const float* __restrict__ W,
                      const float* __restrict__ b, float* __restrict__ outp) {
    int lane = threadIdx.x & 63;
    int tile = blockIdx.x * 4 + (threadIdx.x >> 6);
    if (tile >= NTILE) return;
    int row = lane & 15;                   // A-row / B-col-within-tile
    int kg  = lane >> 4;
    short8v bW[2][3];
    #pragma unroll
    for (int kt = 0; kt < 2; kt++)
        #pragma unroll
        for (int ct = 0; ct < 3; ct++) {
            int col = ct*16 + row;
            #pragma unroll
            for (int j = 0; j < 8; j++)
                bW[kt][ct][j] = (col < NC) ? (short)f2b(W[(kt*32 + kg*8 + j) * NC + col]) : (short)0;
        }
    int node0 = tile * 16;
    const u16* ar = Hm + (size_t)(node0 + row) * HD + kg * 8;
    short8v af0 = *(const short8v*)(ar);
    short8v af1 = *(const short8v*)(ar + 32);
    accf4 acc[3] = {};
    #pragma unroll
    for (int ct = 0; ct < 3; ct++) {
        acc[ct] = __builtin_amdgcn_mfma_f32_16x16x32_bf16(af0, bW[0][ct], acc[ct], 0, 0, 0);
        acc[ct] = __builtin_amdgcn_mfma_f32_16x16x32_bf16(af1, bW[1][ct], acc[ct], 0, 0, 0);
    }
    float bias0 = b[row];
    float bias1 = b[16 + row];
    bool  has2  = (32 + row) < NC;
    float bias2 = has2 ? b[32 + row] : 0.f;
    #pragma unroll
    for (int r = 0; r < 4; r++) {
        float l0 = acc[0][r] + bias0;
        float l1 = acc[1][r] + bias1;
        float l2 = has2 ? acc[2][r] + bias2 : -1e30f;
        float m = fmaxf(fmaxf(l0, l1), l2);
        #pragma unroll
        for (int s2 = 8; s2 > 0; s2 >>= 1) m = fmaxf(m, __shfl_xor(m, s2));
        float sum = expf(l0 - m) + expf(l1 - m) + (has2 ? expf(l2 - m) : 0.f);
        #pragma unroll
        for (int s2 = 8; s2 > 0; s2 >>= 1) sum += __shfl_xor(sum, s2);
        float ls = logf(sum);
        size_t base = (size_t)(node0 + kg*4 + r) * NC;
        outp[base + row]      = (l0 - m) - ls;
        outp[base + 16 + row] = (l1 - m) - ls;
        if (has2) outp[base + 32 + row] = (l2 - m) - ls;
    }
}

// ---------------- launch ----------------

extern "C" void kernel_launch(void* const* d_in, const int* in_sizes, int n_in,
                              void* d_out, int out_size, void* d_ws, size_t ws_size,
                              hipStream_t stream) {
    const float* x   = (const float*)d_in[0];
    const int*   ei  = (const int*)  d_in[1];
    const float* ew  = (const float*)d_in[2];
    const float* Wf  = (const float*)d_in[3];
    const float* bf  = (const float*)d_in[4];
    const float* Wc1 = (const float*)d_in[5];
    const float* bc1 = (const float*)d_in[6];
    const float* Wc2 = (const float*)d_in[7];
    const float* bc2 = (const float*)d_in[8];
    const float* Wo  = (const float*)d_in[9];
    const float* bo  = (const float*)d_in[10];
    float* out = (float*)d_out;

    char* w = (char*)d_ws;
    auto alloc = [&](size_t bytes) {
        char* p = w;
        w += (bytes + 511) & ~(size_t)511;
        return p;
    };
    float* dinv = (float*)alloc((size_t)NN * 4);
    int*   off  = (int*)  alloc((size_t)(NN + 1) * 4);
    int*   bsum = (int*)  alloc((size_t)NB_SCAN * 4);
    uint2* csr  = (uint2*)alloc((size_t)(NE + 128) * 8);  // +128 pad for over-read
    u16*   hA   = (u16*)  alloc((size_t)NN * HD * 2);     // bf16 buffers
    u16*   hB   = (u16*)  alloc((size_t)NN * HD * 2);
    // overlays (dead before hosts' first write, stream-ordered):
    u16* pos    = (u16*)hA;        // dead after k_fill; hA first written by k_lin1
    u32* packed = (u32*)hB;        // dead after k_scan_local; hB first written by k_mm64

    k_count2    <<<NCB, 1024, 0, stream>>>(ei, ew, packed, pos);
    k_scan_local<<<NB_SCAN, 256, 0, stream>>>(packed, off, bsum, dinv);
    k_scan_bsum <<<1, 64, 0, stream>>>(bsum, off);
    k_scan_add  <<<NB_SCAN, 256, 0, stream>>>(off, bsum);
    k_fill      <<<(NE + 255) / 256, 256, 0, stream>>>(ei, ew, dinv, off, pos, csr);

    int mmblocks = (NTILE + 3) / 4;
    k_lin1 <<<mmblocks, 256, 0, stream>>>(x, Wf, bf, hA);
    k_mm64 <<<mmblocks, 256, 0, stream>>>(hA, Wc1, hB);
    k_agg  <<<NN / 16, 256, 0, stream>>>((const u32*)hB, off, csr, dinv, bc1, (uint2*)hA);
    k_mm64 <<<mmblocks, 256, 0, stream>>>(hA, Wc2, hB);
    k_agg  <<<NN / 16, 256, 0, stream>>>((const u32*)hB, off, csr, dinv, bc2, (uint2*)hA);
    k_out  <<<mmblocks, 256, 0, stream>>>(hA, Wo, bo, out);
}

// Round 8
// 228.827 us; speedup vs baseline: 2.8047x; 2.8047x over previous
//
#include <hip/hip_runtime.h>
#include <hip/hip_bf16.h>
#include <cstdint>
#include <cstddef>

#define NN 100000
#define NE 1600000
#define FIN 128
#define HD 64
#define NC 40
#define NTILE (NN / 16)                      // 6250 MFMA row-tiles

#define SCAN_CHUNK 2048
#define NB_SCAN ((NN + SCAN_CHUNK - 1) / SCAN_CHUNK)   // 49

#define EDGE_BLOCKS (NE / 256)               // 6250 (exact)
#define MM_BLOCKS ((NTILE + 3) / 4)          // 1563

typedef unsigned short u16;
typedef unsigned int u32;
typedef __attribute__((ext_vector_type(8))) short short8v;
typedef __attribute__((ext_vector_type(4))) float accf4;

__device__ __forceinline__ float u2lo(u32 u) { return __uint_as_float(u << 16); }
__device__ __forceinline__ float u2hi(u32 u) { return __uint_as_float(u & 0xFFFF0000u); }
__device__ __forceinline__ u16 f2b(float f) {            // RNE f32->bf16
    u32 u = __float_as_uint(f);
    return (u16)((u + 0x7FFFu + ((u >> 16) & 1u)) >> 16);
}

// ---------------- fused: edge count (atomic) || lin1 (MFMA) ----------------
// count: one packed 32-bit atomic per edge: hi-12 = count, lo-20 = Q6.14 wsum.
// lin1:  h(bf16) = relu(x @ W + b), one wave per 16-node tile.
__launch_bounds__(256)
__global__ void k_fuse1(const int* __restrict__ ei, const float* __restrict__ ew,
                        u32* __restrict__ packed, u16* __restrict__ pos,
                        const float* __restrict__ x, const float* __restrict__ W,
                        const float* __restrict__ b, u16* __restrict__ out) {
    if (blockIdx.x < EDGE_BLOCKS) {
        int e = blockIdx.x * 256 + threadIdx.x;
        int c = ei[NE + e];
        u32 fx = __float2uint_rn(ew[e] * 16384.0f);   // Q6.14
        u32 old = atomicAdd(&packed[c], (1u << 20) | fx);
        pos[e] = (u16)(old >> 20);
        return;
    }
    int lane = threadIdx.x & 63;
    int tile = (blockIdx.x - EDGE_BLOCKS) * 4 + (threadIdx.x >> 6);
    if (tile >= NTILE) return;
    int row = lane & 15;                   // A-row (node) / B-col (feature)
    int kg  = lane >> 4;                   // k-group
    short8v bW[4][4];                      // [ktile][coltile]
    #pragma unroll
    for (int kt = 0; kt < 4; kt++)
        #pragma unroll
        for (int ct = 0; ct < 4; ct++)
            #pragma unroll
            for (int j = 0; j < 8; j++)
                bW[kt][ct][j] = (short)f2b(W[(kt*32 + kg*8 + j) * HD + ct*16 + row]);
    int node0 = tile * 16;
    const float* xr = x + (size_t)(node0 + row) * FIN + kg * 8;
    float4 xa[4][2];
    #pragma unroll
    for (int kt = 0; kt < 4; kt++) {
        xa[kt][0] = *(const float4*)(xr + kt*32);
        xa[kt][1] = *(const float4*)(xr + kt*32 + 4);
    }
    short8v af[4];
    #pragma unroll
    for (int kt = 0; kt < 4; kt++) {
        af[kt][0] = (short)f2b(xa[kt][0].x); af[kt][1] = (short)f2b(xa[kt][0].y);
        af[kt][2] = (short)f2b(xa[kt][0].z); af[kt][3] = (short)f2b(xa[kt][0].w);
        af[kt][4] = (short)f2b(xa[kt][1].x); af[kt][5] = (short)f2b(xa[kt][1].y);
        af[kt][6] = (short)f2b(xa[kt][1].z); af[kt][7] = (short)f2b(xa[kt][1].w);
    }
    accf4 acc[4] = {};
    #pragma unroll
    for (int kt = 0; kt < 4; kt++)
        #pragma unroll
        for (int ct = 0; ct < 4; ct++)
            acc[ct] = __builtin_amdgcn_mfma_f32_16x16x32_bf16(af[kt], bW[kt][ct], acc[ct], 0, 0, 0);
    #pragma unroll
    for (int ct = 0; ct < 4; ct++) {
        float bias = b[ct*16 + row];
        #pragma unroll
        for (int r = 0; r < 4; r++) {
            float v = fmaxf(acc[ct][r] + bias, 0.f);
            out[(size_t)(node0 + kg*4 + r) * HD + ct*16 + row] = f2b(v);
        }
    }
}

// ---- two-level exclusive scan over counts (packed hi-12) -> off; also emits dinv ----

__launch_bounds__(256)
__global__ void k_scan_local(const u32* __restrict__ packed, int* __restrict__ off,
                             int* __restrict__ bsum, float* __restrict__ dinv) {
    __shared__ int wtot[4];
    int tid = threadIdx.x, lane = tid & 63, wid = tid >> 6;
    int base = blockIdx.x * SCAN_CHUNK + tid * 8;
    int v[8];
    int s = 0;
    #pragma unroll
    for (int i = 0; i < 8; i++) {
        if (base + i < NN) {
            u32 p = packed[base + i];
            v[i] = (int)(p >> 20);
            float deg = 1.0f + (float)(p & 0xFFFFFu) * (1.0f / 16384.0f);
            dinv[base + i] = rsqrtf(deg);
        } else v[i] = 0;
    }
    #pragma unroll
    for (int i = 0; i < 8; i++) s += v[i];
    int inc = s;
    #pragma unroll
    for (int d = 1; d < 64; d <<= 1) {
        int t = __shfl_up(inc, d);
        if (lane >= d) inc += t;
    }
    if (lane == 63) wtot[wid] = inc;
    __syncthreads();
    int wof = 0;
    #pragma unroll
    for (int k = 0; k < 4; k++) if (k < wid) wof += wtot[k];
    int run = wof + inc - s;
    #pragma unroll
    for (int i = 0; i < 8; i++) {
        if (base + i < NN) off[base + i] = run;
        run += v[i];
    }
    if (tid == 255) bsum[blockIdx.x] = wof + inc;
}

__global__ void k_scan_bsum(int* __restrict__ bsum, int* __restrict__ off) {
    int lane = threadIdx.x;
    int v = (lane < NB_SCAN) ? bsum[lane] : 0;
    int inc = v;
    #pragma unroll
    for (int d = 1; d < 64; d <<= 1) {
        int t = __shfl_up(inc, d);
        if (lane >= d) inc += t;
    }
    if (lane < NB_SCAN) bsum[lane] = inc - v;
    if (lane == 63) off[NN] = inc;
}

__launch_bounds__(256)
__global__ void k_scan_add(int* __restrict__ off, const int* __restrict__ bsum) {
    int carry = bsum[blockIdx.x];
    int base = blockIdx.x * SCAN_CHUNK + threadIdx.x * 8;
    if (base + 7 < NN) {
        int4* p = (int4*)(off + base);
        int4 a = p[0], b = p[1];
        a.x+=carry; a.y+=carry; a.z+=carry; a.w+=carry;
        b.x+=carry; b.y+=carry; b.z+=carry; b.w+=carry;
        p[0] = a; p[1] = b;
    } else {
        for (int i = 0; i < 8 && base + i < NN; i++) off[base + i] += carry;
    }
}

// ---------------- fused: csr fill || mm64 conv1 (MFMA) ----------------
// fill: atomic-free, slot = off[col] + pos[e]; one fused 8B store.
// mm64: out(bf16) = A(bf16) @ W, [NN,64]@[64,64].
__launch_bounds__(256)
__global__ void k_fuse2(const int* __restrict__ ei, const float* __restrict__ ew,
                        const float* __restrict__ dinv, const int* __restrict__ off,
                        const u16* __restrict__ pos, uint2* __restrict__ csr,
                        const u16* __restrict__ A, const float* __restrict__ W,
                        u16* __restrict__ out) {
    if (blockIdx.x < EDGE_BLOCKS) {
        int e = blockIdx.x * 256 + threadIdx.x;
        int r = ei[e], c = ei[NE + e];
        float nv = dinv[r] * ew[e] * dinv[c];
        int slot = off[c] + (int)pos[e];
        csr[slot] = make_uint2((u32)r, __float_as_uint(nv));
        return;
    }
    int lane = threadIdx.x & 63;
    int tile = (blockIdx.x - EDGE_BLOCKS) * 4 + (threadIdx.x >> 6);
    if (tile >= NTILE) return;
    int row = lane & 15;
    int kg  = lane >> 4;
    short8v bW[2][4];
    #pragma unroll
    for (int kt = 0; kt < 2; kt++)
        #pragma unroll
        for (int ct = 0; ct < 4; ct++)
            #pragma unroll
            for (int j = 0; j < 8; j++)
                bW[kt][ct][j] = (short)f2b(W[(kt*32 + kg*8 + j) * HD + ct*16 + row]);
    int node0 = tile * 16;
    const u16* ar = A + (size_t)(node0 + row) * HD + kg * 8;
    short8v af0 = *(const short8v*)(ar);
    short8v af1 = *(const short8v*)(ar + 32);
    accf4 acc[4] = {};
    #pragma unroll
    for (int ct = 0; ct < 4; ct++) {
        acc[ct] = __builtin_amdgcn_mfma_f32_16x16x32_bf16(af0, bW[0][ct], acc[ct], 0, 0, 0);
        acc[ct] = __builtin_amdgcn_mfma_f32_16x16x32_bf16(af1, bW[1][ct], acc[ct], 0, 0, 0);
    }
    #pragma unroll
    for (int ct = 0; ct < 4; ct++)
        #pragma unroll
        for (int r = 0; r < 4; r++)
            out[(size_t)(node0 + kg*4 + r) * HD + ct*16 + row] = f2b(acc[ct][r]);
}

// out(bf16) = A(bf16) @ W (no bias): [NN,64]@[64,64]  (standalone, conv2)
__launch_bounds__(256)
__global__ void k_mm64(const u16* __restrict__ A, const float* __restrict__ W,
                       u16* __restrict__ out) {
    int lane = threadIdx.x & 63;
    int tile = blockIdx.x * 4 + (threadIdx.x >> 6);
    if (tile >= NTILE) return;
    int row = lane & 15;
    int kg  = lane >> 4;
    short8v bW[2][4];
    #pragma unroll
    for (int kt = 0; kt < 2; kt++)
        #pragma unroll
        for (int ct = 0; ct < 4; ct++)
            #pragma unroll
            for (int j = 0; j < 8; j++)
                bW[kt][ct][j] = (short)f2b(W[(kt*32 + kg*8 + j) * HD + ct*16 + row]);
    int node0 = tile * 16;
    const u16* ar = A + (size_t)(node0 + row) * HD + kg * 8;
    short8v af0 = *(const short8v*)(ar);
    short8v af1 = *(const short8v*)(ar + 32);
    accf4 acc[4] = {};
    #pragma unroll
    for (int ct = 0; ct < 4; ct++) {
        acc[ct] = __builtin_amdgcn_mfma_f32_16x16x32_bf16(af0, bW[0][ct], acc[ct], 0, 0, 0);
        acc[ct] = __builtin_amdgcn_mfma_f32_16x16x32_bf16(af1, bW[1][ct], acc[ct], 0, 0, 0);
    }
    #pragma unroll
    for (int ct = 0; ct < 4; ct++)
        #pragma unroll
        for (int r = 0; r < 4; r++)
            out[(size_t)(node0 + kg*4 + r) * HD + ct*16 + row] = f2b(acc[ct][r]);
}

// out(bf16) = relu(Ahat @ Bm + bias): 4 nodes/wave, 16 lanes/row, csr prefetch
__launch_bounds__(256)
__global__ void k_agg(const u32* __restrict__ Bm2, const int* __restrict__ off,
                      const uint2* __restrict__ csr, const float* __restrict__ dinv,
                      const float* __restrict__ bias, uint2* __restrict__ outp) {
    int lane = threadIdx.x & 63;
    int wave = threadIdx.x >> 6;
    int q    = lane >> 4;
    int fp   = lane & 15;
    int node = blockIdx.x * 16 + wave * 4 + q;
    int s = off[node], e = off[node + 1];
    int deg = e - s;
    float di = dinv[node];
    float sc = di * di;
    uint2 sw = *(const uint2*)(Bm2 + (size_t)node * 32 + fp * 2);
    float4 acc;
    acc.x = sc * u2lo(sw.x); acc.y = sc * u2hi(sw.x);
    acc.z = sc * u2lo(sw.y); acc.w = sc * u2hi(sw.y);
    uint2 c0 = csr[s+0], c1 = csr[s+1], c2 = csr[s+2], c3 = csr[s+3];
    for (int j = 0; __any(j < deg); j += 4) {
        // prefetch next chunk (csr +128 pad keeps over-reads in-bounds)
        uint2 n0 = csr[s+j+4], n1 = csr[s+j+5], n2 = csr[s+j+6], n3 = csr[s+j+7];
        bool a0 = (j+0) < deg; u32 r0 = a0 ? c0.x : (u32)node; float w0 = a0 ? __uint_as_float(c0.y) : 0.f;
        bool a1 = (j+1) < deg; u32 r1 = a1 ? c1.x : (u32)node; float w1 = a1 ? __uint_as_float(c1.y) : 0.f;
        bool a2 = (j+2) < deg; u32 r2 = a2 ? c2.x : (u32)node; float w2 = a2 ? __uint_as_float(c2.y) : 0.f;
        bool a3 = (j+3) < deg; u32 r3 = a3 ? c3.x : (u32)node; float w3 = a3 ? __uint_as_float(c3.y) : 0.f;
        uint2 g0 = *(const uint2*)(Bm2 + (size_t)r0 * 32 + fp * 2);
        uint2 g1 = *(const uint2*)(Bm2 + (size_t)r1 * 32 + fp * 2);
        uint2 g2 = *(const uint2*)(Bm2 + (size_t)r2 * 32 + fp * 2);
        uint2 g3 = *(const uint2*)(Bm2 + (size_t)r3 * 32 + fp * 2);
        acc.x += w0 * u2lo(g0.x) + w1 * u2lo(g1.x);
        acc.y += w0 * u2hi(g0.x) + w1 * u2hi(g1.x);
        acc.z += w0 * u2lo(g0.y) + w1 * u2lo(g1.y);
        acc.w += w0 * u2hi(g0.y) + w1 * u2hi(g1.y);
        acc.x += w2 * u2lo(g2.x) + w3 * u2lo(g3.x);
        acc.y += w2 * u2hi(g2.x) + w3 * u2hi(g3.x);
        acc.z += w2 * u2lo(g2.y) + w3 * u2lo(g3.y);
        acc.w += w2 * u2hi(g2.y) + w3 * u2hi(g3.y);
        c0 = n0; c1 = n1; c2 = n2; c3 = n3;
    }
    float4 bv = *(const float4*)(bias + fp * 4);
    uint2 ov;
    ov.x = (u32)f2b(fmaxf(acc.x + bv.x, 0.f)) | ((u32)f2b(fmaxf(acc.y + bv.y, 0.f)) << 16);
    ov.y = (u32)f2b(fmaxf(acc.z + bv.z, 0.f)) | ((u32)f2b(fmaxf(acc.w + bv.w, 0.f)) << 16);
    outp[(size_t)node * 16 + fp] = ov;
}

// logits = H(bf16) @ Wo + bo ; out = log_softmax (MFMA, 3 col-tiles, zero-padded)
__launch_bounds__(256)
__global__ void k_out(const u16* __restrict__ Hm, const float* __restrict__ W,
                      const float* __restrict__ b, float* __restrict__ outp) {
    int lane = threadIdx.x & 63;
    int tile = blockIdx.x * 4 + (threadIdx.x >> 6);
    if (tile >= NTILE) return;
    int row = lane & 15;                   // A-row / B-col-within-tile
    int kg  = lane >> 4;
    short8v bW[2][3];
    #pragma unroll
    for (int kt = 0; kt < 2; kt++)
        #pragma unroll
        for (int ct = 0; ct < 3; ct++) {
            int col = ct*16 + row;
            #pragma unroll
            for (int j = 0; j < 8; j++)
                bW[kt][ct][j] = (col < NC) ? (short)f2b(W[(kt*32 + kg*8 + j) * NC + col]) : (short)0;
        }
    int node0 = tile * 16;
    const u16* ar = Hm + (size_t)(node0 + row) * HD + kg * 8;
    short8v af0 = *(const short8v*)(ar);
    short8v af1 = *(const short8v*)(ar + 32);
    accf4 acc[3] = {};
    #pragma unroll
    for (int ct = 0; ct < 3; ct++) {
        acc[ct] = __builtin_amdgcn_mfma_f32_16x16x32_bf16(af0, bW[0][ct], acc[ct], 0, 0, 0);
        acc[ct] = __builtin_amdgcn_mfma_f32_16x16x32_bf16(af1, bW[1][ct], acc[ct], 0, 0, 0);
    }
    float bias0 = b[row];
    float bias1 = b[16 + row];
    bool  has2  = (32 + row) < NC;
    float bias2 = has2 ? b[32 + row] : 0.f;
    #pragma unroll
    for (int r = 0; r < 4; r++) {
        float l0 = acc[0][r] + bias0;
        float l1 = acc[1][r] + bias1;
        float l2 = has2 ? acc[2][r] + bias2 : -1e30f;
        float m = fmaxf(fmaxf(l0, l1), l2);
        #pragma unroll
        for (int s2 = 8; s2 > 0; s2 >>= 1) m = fmaxf(m, __shfl_xor(m, s2));
        float sum = expf(l0 - m) + expf(l1 - m) + (has2 ? expf(l2 - m) : 0.f);
        #pragma unroll
        for (int s2 = 8; s2 > 0; s2 >>= 1) sum += __shfl_xor(sum, s2);
        float ls = logf(sum);
        size_t base = (size_t)(node0 + kg*4 + r) * NC;
        outp[base + row]      = (l0 - m) - ls;
        outp[base + 16 + row] = (l1 - m) - ls;
        if (has2) outp[base + 32 + row] = (l2 - m) - ls;
    }
}

// ---------------- launch ----------------

extern "C" void kernel_launch(void* const* d_in, const int* in_sizes, int n_in,
                              void* d_out, int out_size, void* d_ws, size_t ws_size,
                              hipStream_t stream) {
    const float* x   = (const float*)d_in[0];
    const int*   ei  = (const int*)  d_in[1];
    const float* ew  = (const float*)d_in[2];
    const float* Wf  = (const float*)d_in[3];
    const float* bf  = (const float*)d_in[4];
    const float* Wc1 = (const float*)d_in[5];
    const float* bc1 = (const float*)d_in[6];
    const float* Wc2 = (const float*)d_in[7];
    const float* bc2 = (const float*)d_in[8];
    const float* Wo  = (const float*)d_in[9];
    const float* bo  = (const float*)d_in[10];
    float* out = (float*)d_out;

    char* w = (char*)d_ws;
    auto alloc = [&](size_t bytes) {
        char* p = w;
        w += (bytes + 511) & ~(size_t)511;
        return p;
    };
    float* dinv = (float*)alloc((size_t)NN * 4);
    int*   off  = (int*)  alloc((size_t)(NN + 1) * 4);
    int*   bsum = (int*)  alloc((size_t)NB_SCAN * 4);
    u16*   pos  = (u16*)  alloc((size_t)NE * 2);          // own allocation (fuse1 races hA)
    uint2* csr  = (uint2*)alloc((size_t)(NE + 128) * 8);  // +128 pad for over-read
    u16*   hA   = (u16*)  alloc((size_t)NN * HD * 2);     // bf16 buffers
    u16*   hB   = (u16*)  alloc((size_t)NN * HD * 2);
    // overlay: packed dead after k_scan_local; hB first written by k_fuse2 (mm64 half)
    u32* packed = (u32*)hB;

    hipMemsetAsync(packed, 0, (size_t)NN * 4, stream);
    k_fuse1     <<<EDGE_BLOCKS + MM_BLOCKS, 256, 0, stream>>>(ei, ew, packed, pos, x, Wf, bf, hA);
    k_scan_local<<<NB_SCAN, 256, 0, stream>>>(packed, off, bsum, dinv);
    k_scan_bsum <<<1, 64, 0, stream>>>(bsum, off);
    k_scan_add  <<<NB_SCAN, 256, 0, stream>>>(off, bsum);
    k_fuse2     <<<EDGE_BLOCKS + MM_BLOCKS, 256, 0, stream>>>(ei, ew, dinv, off, pos, csr, hA, Wc1, hB);
    k_agg       <<<NN / 16, 256, 0, stream>>>((const u32*)hB, off, csr, dinv, bc1, (uint2*)hA);
    k_mm64      <<<MM_BLOCKS, 256, 0, stream>>>(hA, Wc2, hB);
    k_agg       <<<NN / 16, 256, 0, stream>>>((const u32*)hB, off, csr, dinv, bc2, (uint2*)hA);
    k_out       <<<MM_BLOCKS, 256, 0, stream>>>(hA, Wo, bo, out);
}

// Round 9
// 184.971 us; speedup vs baseline: 3.4697x; 1.2371x over previous
//
#include <hip/hip_runtime.h>
#include <hip/hip_bf16.h>
#include <cstdint>
#include <cstddef>

#define NN 100000
#define NE 1600000
#define FIN 128
#define HD 64
#define NC 40
#define NTILE (NN / 16)                      // 6250 MFMA row-tiles
#define MM_BLOCKS ((NTILE + 3) / 4)          // 1563

#define BUK 256                              // nodes per bucket
#define NBUK ((NN + BUK - 1) / BUK)          // 391
#define EPB 4096                             // edges per hist/scatter block
#define NBLK ((NE + EPB - 1) / EPB)          // 391

typedef unsigned short u16;
typedef unsigned int u32;
typedef __attribute__((ext_vector_type(8))) short short8v;
typedef __attribute__((ext_vector_type(4))) float accf4;

__device__ __forceinline__ float u2lo(u32 u) { return __uint_as_float(u << 16); }
__device__ __forceinline__ float u2hi(u32 u) { return __uint_as_float(u & 0xFFFF0000u); }
__device__ __forceinline__ u16 f2b(float f) {            // RNE f32->bf16
    u32 u = __float_as_uint(f);
    return (u16)((u + 0x7FFFu + ((u >> 16) & 1u)) >> 16);
}

// ------- fused: per-block bucket histogram (LDS, no global atomics) || lin1 -------
__launch_bounds__(256)
__global__ void k_build1(const int* __restrict__ ei, u32* __restrict__ hist,
                         const float* __restrict__ x, const float* __restrict__ W,
                         const float* __restrict__ b, u16* __restrict__ out) {
    if (blockIdx.x < NBLK) {
        __shared__ u32 lh[NBUK];
        int blk = blockIdx.x, tid = threadIdx.x;
        for (int i = tid; i < NBUK; i += 256) lh[i] = 0;
        __syncthreads();
        #pragma unroll
        for (int it = 0; it < EPB / 256; it++) {
            int e = blk * EPB + it * 256 + tid;
            if (e < NE) {
                int col = ei[NE + e];
                atomicAdd(&lh[col >> 8], 1u);
            }
        }
        __syncthreads();
        for (int i = tid; i < NBUK; i += 256) hist[(size_t)i * NBLK + blk] = lh[i];
        return;
    }
    // ---- lin1 half: h(bf16) = relu(x @ W + b), one wave per 16-node tile ----
    int lane = threadIdx.x & 63;
    int tile = (blockIdx.x - NBLK) * 4 + (threadIdx.x >> 6);
    if (tile >= NTILE) return;
    int row = lane & 15;
    int kg  = lane >> 4;
    short8v bW[4][4];
    #pragma unroll
    for (int kt = 0; kt < 4; kt++)
        #pragma unroll
        for (int ct = 0; ct < 4; ct++)
            #pragma unroll
            for (int j = 0; j < 8; j++)
                bW[kt][ct][j] = (short)f2b(W[(kt*32 + kg*8 + j) * HD + ct*16 + row]);
    int node0 = tile * 16;
    const float* xr = x + (size_t)(node0 + row) * FIN + kg * 8;
    float4 xa[4][2];
    #pragma unroll
    for (int kt = 0; kt < 4; kt++) {
        xa[kt][0] = *(const float4*)(xr + kt*32);
        xa[kt][1] = *(const float4*)(xr + kt*32 + 4);
    }
    short8v af[4];
    #pragma unroll
    for (int kt = 0; kt < 4; kt++) {
        af[kt][0] = (short)f2b(xa[kt][0].x); af[kt][1] = (short)f2b(xa[kt][0].y);
        af[kt][2] = (short)f2b(xa[kt][0].z); af[kt][3] = (short)f2b(xa[kt][0].w);
        af[kt][4] = (short)f2b(xa[kt][1].x); af[kt][5] = (short)f2b(xa[kt][1].y);
        af[kt][6] = (short)f2b(xa[kt][1].z); af[kt][7] = (short)f2b(xa[kt][1].w);
    }
    accf4 acc[4] = {};
    #pragma unroll
    for (int kt = 0; kt < 4; kt++)
        #pragma unroll
        for (int ct = 0; ct < 4; ct++)
            acc[ct] = __builtin_amdgcn_mfma_f32_16x16x32_bf16(af[kt], bW[kt][ct], acc[ct], 0, 0, 0);
    #pragma unroll
    for (int ct = 0; ct < 4; ct++) {
        float bias = b[ct*16 + row];
        #pragma unroll
        for (int r = 0; r < 4; r++) {
            float v = fmaxf(acc[ct][r] + bias, 0.f);
            out[(size_t)(node0 + kg*4 + r) * HD + ct*16 + row] = f2b(v);
        }
    }
}

// per-bucket exclusive prefix over blocks (in place); total -> bucketTotal
__global__ void k_bscan(u32* __restrict__ hist, u32* __restrict__ bucketTotal) {
    int b = blockIdx.x;
    int lane = threadIdx.x;                  // 64 threads
    u32* h = hist + (size_t)b * NBLK;
    u32 carry = 0;
    for (int j0 = 0; j0 < NBLK; j0 += 64) {
        int j = j0 + lane;
        u32 v = (j < NBLK) ? h[j] : 0;
        u32 inc = v;
        #pragma unroll
        for (int d = 1; d < 64; d <<= 1) {
            u32 t = __shfl_up(inc, d);
            if (lane >= d) inc += t;
        }
        if (j < NBLK) h[j] = carry + inc - v;
        carry += __shfl(inc, 63);
    }
    if (lane == 0) bucketTotal[b] = carry;
}

// scan bucketTotal -> bucketStart (exclusive); bucketStart[NBUK]=NE; off[NN]=NE
__global__ void k_bstart(const u32* __restrict__ bucketTotal, u32* __restrict__ bucketStart,
                         int* __restrict__ off) {
    int lane = threadIdx.x;                  // 64 threads
    u32 carry = 0;
    for (int j0 = 0; j0 < NBUK; j0 += 64) {
        int j = j0 + lane;
        u32 v = (j < NBUK) ? bucketTotal[j] : 0;
        u32 inc = v;
        #pragma unroll
        for (int d = 1; d < 64; d <<= 1) {
            u32 t = __shfl_up(inc, d);
            if (lane >= d) inc += t;
        }
        if (j < NBUK) bucketStart[j] = carry + inc - v;
        carry += __shfl(inc, 63);
    }
    if (lane == 0) { bucketStart[NBUK] = carry; off[NN] = (int)carry; }
}

// scatter edges into bucket segments: rank via LDS atomics (no global atomics)
__launch_bounds__(256)
__global__ void k_scatter(const int* __restrict__ ei, const float* __restrict__ ew,
                          const u32* __restrict__ hist, const u32* __restrict__ bucketStart,
                          uint2* __restrict__ recAB, u32* __restrict__ recC) {
    __shared__ u32 lh[NBUK];
    __shared__ u32 gb[NBUK];
    int blk = blockIdx.x, tid = threadIdx.x;
    for (int i = tid; i < NBUK; i += 256) {
        lh[i] = 0;
        gb[i] = bucketStart[i] + hist[(size_t)i * NBLK + blk];
    }
    __syncthreads();
    #pragma unroll
    for (int it = 0; it < EPB / 256; it++) {
        int e = blk * EPB + it * 256 + tid;
        if (e < NE) {
            int row = ei[e], col = ei[NE + e];
            float wv = ew[e];
            int bkt = col >> 8;
            u32 r = atomicAdd(&lh[bkt], 1u);
            u32 slot = gb[bkt] + r;
            recAB[slot] = make_uint2((u32)row, __float_as_uint(wv));
            recC[slot]  = (u32)col;
        }
    }
}

// per-bucket CSR build: packed LDS hist -> dinv, off, csr=(row, raw ew)
__launch_bounds__(256)
__global__ void k_bucket(const uint2* __restrict__ recAB, const u32* __restrict__ recC,
                         const u32* __restrict__ bucketStart, float* __restrict__ dinv,
                         int* __restrict__ off, uint2* __restrict__ csr) {
    __shared__ u32 lpk[BUK];
    __shared__ u32 loff[BUK];
    __shared__ u32 wt[4];
    int b = blockIdx.x, tid = threadIdx.x;
    int base = b * BUK;
    u32 seg0 = bucketStart[b], seg1 = bucketStart[b + 1];
    int nb = (int)(seg1 - seg0);
    lpk[tid] = 0;
    __syncthreads();
    for (int idx = tid; idx < nb; idx += 256) {
        uint2 ab = recAB[seg0 + idx];
        u32 cl = recC[seg0 + idx] - base;
        u32 fx = __float2uint_rn(__uint_as_float(ab.y) * 16384.0f);   // Q6.14
        atomicAdd(&lpk[cl], (1u << 20) | fx);
    }
    __syncthreads();
    u32 pk = lpk[tid];
    u32 cnt = pk >> 20;
    int node = base + tid;
    if (node < NN) dinv[node] = rsqrtf(1.0f + (float)(pk & 0xFFFFFu) * (1.0f / 16384.0f));
    // exclusive scan of cnt over 256
    int lane = tid & 63, wid = tid >> 6;
    u32 inc = cnt;
    #pragma unroll
    for (int d = 1; d < 64; d <<= 1) {
        u32 t = __shfl_up(inc, d);
        if (lane >= d) inc += t;
    }
    if (lane == 63) wt[wid] = inc;
    __syncthreads();
    u32 wof = 0;
    #pragma unroll
    for (int k = 0; k < 4; k++) if (k < wid) wof += wt[k];
    loff[tid] = wof + inc - cnt;
    if (node < NN) off[node] = (int)(seg0 + loff[tid]);
    lpk[tid] = 0;                    // reuse as rank counters
    __syncthreads();
    for (int idx = tid; idx < nb; idx += 256) {
        uint2 ab = recAB[seg0 + idx];
        u32 cl = recC[seg0 + idx] - base;
        u32 r2 = atomicAdd(&lpk[cl], 1u);
        csr[seg0 + loff[cl] + r2] = ab;          // (row, raw ew)
    }
}

// out(bf16) = dinv-scaled A(bf16) @ W: tbl'[r] = dinv[r] * (A@W)[r]
__launch_bounds__(256)
__global__ void k_mm64(const u16* __restrict__ A, const float* __restrict__ W,
                       const float* __restrict__ dinv, u16* __restrict__ out) {
    int lane = threadIdx.x & 63;
    int tile = blockIdx.x * 4 + (threadIdx.x >> 6);
    if (tile >= NTILE) return;
    int row = lane & 15;
    int kg  = lane >> 4;
    short8v bW[2][4];
    #pragma unroll
    for (int kt = 0; kt < 2; kt++)
        #pragma unroll
        for (int ct = 0; ct < 4; ct++)
            #pragma unroll
            for (int j = 0; j < 8; j++)
                bW[kt][ct][j] = (short)f2b(W[(kt*32 + kg*8 + j) * HD + ct*16 + row]);
    int node0 = tile * 16;
    const u16* ar = A + (size_t)(node0 + row) * HD + kg * 8;
    short8v af0 = *(const short8v*)(ar);
    short8v af1 = *(const short8v*)(ar + 32);
    accf4 acc[4] = {};
    #pragma unroll
    for (int ct = 0; ct < 4; ct++) {
        acc[ct] = __builtin_amdgcn_mfma_f32_16x16x32_bf16(af0, bW[0][ct], acc[ct], 0, 0, 0);
        acc[ct] = __builtin_amdgcn_mfma_f32_16x16x32_bf16(af1, bW[1][ct], acc[ct], 0, 0, 0);
    }
    float dr[4];
    #pragma unroll
    for (int r = 0; r < 4; r++) dr[r] = dinv[node0 + kg*4 + r];
    #pragma unroll
    for (int ct = 0; ct < 4; ct++)
        #pragma unroll
        for (int r = 0; r < 4; r++)
            out[(size_t)(node0 + kg*4 + r) * HD + ct*16 + row] = f2b(acc[ct][r] * dr[r]);
}

// out(bf16) = relu( dinv_c * (tbl'[c] + sum_e ew * tbl'[r]) + bias )
__launch_bounds__(256)
__global__ void k_agg(const u32* __restrict__ Bm2, const int* __restrict__ off,
                      const uint2* __restrict__ csr, const float* __restrict__ dinv,
                      const float* __restrict__ bias, uint2* __restrict__ outp) {
    int lane = threadIdx.x & 63;
    int wave = threadIdx.x >> 6;
    int q    = lane >> 4;
    int fp   = lane & 15;
    int node = blockIdx.x * 16 + wave * 4 + q;
    int s = off[node], e = off[node + 1];
    int deg = e - s;
    float di = dinv[node];
    uint2 sw = *(const uint2*)(Bm2 + (size_t)node * 32 + fp * 2);
    float4 acc;
    acc.x = u2lo(sw.x); acc.y = u2hi(sw.x);      // self-loop, weight 1
    acc.z = u2lo(sw.y); acc.w = u2hi(sw.y);
    uint2 c0 = csr[s+0], c1 = csr[s+1], c2 = csr[s+2], c3 = csr[s+3];
    for (int j = 0; __any(j < deg); j += 4) {
        uint2 n0 = csr[s+j+4], n1 = csr[s+j+5], n2 = csr[s+j+6], n3 = csr[s+j+7];
        bool a0 = (j+0) < deg; u32 r0 = a0 ? c0.x : (u32)node; float w0 = a0 ? __uint_as_float(c0.y) : 0.f;
        bool a1 = (j+1) < deg; u32 r1 = a1 ? c1.x : (u32)node; float w1 = a1 ? __uint_as_float(c1.y) : 0.f;
        bool a2 = (j+2) < deg; u32 r2 = a2 ? c2.x : (u32)node; float w2 = a2 ? __uint_as_float(c2.y) : 0.f;
        bool a3 = (j+3) < deg; u32 r3 = a3 ? c3.x : (u32)node; float w3 = a3 ? __uint_as_float(c3.y) : 0.f;
        uint2 g0 = *(const uint2*)(Bm2 + (size_t)r0 * 32 + fp * 2);
        uint2 g1 = *(const uint2*)(Bm2 + (size_t)r1 * 32 + fp * 2);
        uint2 g2 = *(const uint2*)(Bm2 + (size_t)r2 * 32 + fp * 2);
        uint2 g3 = *(const uint2*)(Bm2 + (size_t)r3 * 32 + fp * 2);
        acc.x += w0 * u2lo(g0.x) + w1 * u2lo(g1.x);
        acc.y += w0 * u2hi(g0.x) + w1 * u2hi(g1.x);
        acc.z += w0 * u2lo(g0.y) + w1 * u2lo(g1.y);
        acc.w += w0 * u2hi(g0.y) + w1 * u2hi(g1.y);
        acc.x += w2 * u2lo(g2.x) + w3 * u2lo(g3.x);
        acc.y += w2 * u2hi(g2.x) + w3 * u2hi(g3.x);
        acc.z += w2 * u2lo(g2.y) + w3 * u2lo(g3.y);
        acc.w += w2 * u2hi(g2.y) + w3 * u2hi(g3.y);
        c0 = n0; c1 = n1; c2 = n2; c3 = n3;
    }
    float4 bv = *(const float4*)(bias + fp * 4);
    uint2 ov;
    ov.x = (u32)f2b(fmaxf(di * acc.x + bv.x, 0.f)) | ((u32)f2b(fmaxf(di * acc.y + bv.y, 0.f)) << 16);
    ov.y = (u32)f2b(fmaxf(di * acc.z + bv.z, 0.f)) | ((u32)f2b(fmaxf(di * acc.w + bv.w, 0.f)) << 16);
    outp[(size_t)node * 16 + fp] = ov;
}

// logits = H(bf16) @ Wo + bo ; out = log_softmax (MFMA, 3 col-tiles, zero-padded)
__launch_bounds__(256)
__global__ void k_out(const u16* __restrict__ Hm, const float* __restrict__ W,
                      const float* __restrict__ b, float* __restrict__ outp) {
    int lane = threadIdx.x & 63;
    int tile = blockIdx.x * 4 + (threadIdx.x >> 6);
    if (tile >= NTILE) return;
    int row = lane & 15;
    int kg  = lane >> 4;
    short8v bW[2][3];
    #pragma unroll
    for (int kt = 0; kt < 2; kt++)
        #pragma unroll
        for (int ct = 0; ct < 3; ct++) {
            int col = ct*16 + row;
            #pragma unroll
            for (int j = 0; j < 8; j++)
                bW[kt][ct][j] = (col < NC) ? (short)f2b(W[(kt*32 + kg*8 + j) * NC + col]) : (short)0;
        }
    int node0 = tile * 16;
    const u16* ar = Hm + (size_t)(node0 + row) * HD + kg * 8;
    short8v af0 = *(const short8v*)(ar);
    short8v af1 = *(const short8v*)(ar + 32);
    accf4 acc[3] = {};
    #pragma unroll
    for (int ct = 0; ct < 3; ct++) {
        acc[ct] = __builtin_amdgcn_mfma_f32_16x16x32_bf16(af0, bW[0][ct], acc[ct], 0, 0, 0);
        acc[ct] = __builtin_amdgcn_mfma_f32_16x16x32_bf16(af1, bW[1][ct], acc[ct], 0, 0, 0);
    }
    float bias0 = b[row];
    float bias1 = b[16 + row];
    bool  has2  = (32 + row) < NC;
    float bias2 = has2 ? b[32 + row] : 0.f;
    #pragma unroll
    for (int r = 0; r < 4; r++) {
        float l0 = acc[0][r] + bias0;
        float l1 = acc[1][r] + bias1;
        float l2 = has2 ? acc[2][r] + bias2 : -1e30f;
        float m = fmaxf(fmaxf(l0, l1), l2);
        #pragma unroll
        for (int s2 = 8; s2 > 0; s2 >>= 1) m = fmaxf(m, __shfl_xor(m, s2));
        float sum = expf(l0 - m) + expf(l1 - m) + (has2 ? expf(l2 - m) : 0.f);
        #pragma unroll
        for (int s2 = 8; s2 > 0; s2 >>= 1) sum += __shfl_xor(sum, s2);
        float ls = logf(sum);
        size_t base = (size_t)(node0 + kg*4 + r) * NC;
        outp[base + row]      = (l0 - m) - ls;
        outp[base + 16 + row] = (l1 - m) - ls;
        if (has2) outp[base + 32 + row] = (l2 - m) - ls;
    }
}

// ---------------- launch ----------------

extern "C" void kernel_launch(void* const* d_in, const int* in_sizes, int n_in,
                              void* d_out, int out_size, void* d_ws, size_t ws_size,
                              hipStream_t stream) {
    const float* x   = (const float*)d_in[0];
    const int*   ei  = (const int*)  d_in[1];
    const float* ew  = (const float*)d_in[2];
    const float* Wf  = (const float*)d_in[3];
    const float* bf  = (const float*)d_in[4];
    const float* Wc1 = (const float*)d_in[5];
    const float* bc1 = (const float*)d_in[6];
    const float* Wc2 = (const float*)d_in[7];
    const float* bc2 = (const float*)d_in[8];
    const float* Wo  = (const float*)d_in[9];
    const float* bo  = (const float*)d_in[10];
    float* out = (float*)d_out;

    char* w = (char*)d_ws;
    auto alloc = [&](size_t bytes) {
        char* p = w;
        w += (bytes + 511) & ~(size_t)511;
        return p;
    };
    u32*   hist  = (u32*)  alloc((size_t)NBUK * NBLK * 4);
    u32*   btot  = (u32*)  alloc((size_t)NBUK * 4);
    u32*   bst   = (u32*)  alloc((size_t)(NBUK + 1) * 4);
    float* dinv  = (float*)alloc((size_t)NN * 4);
    int*   off   = (int*)  alloc((size_t)(NN + 1) * 4);
    uint2* recAB = (uint2*)alloc((size_t)NE * 8);
    u32*   recC  = (u32*)  alloc((size_t)NE * 4);
    uint2* csr   = (uint2*)alloc((size_t)(NE + 128) * 8);  // +128 pad for over-read
    u16*   hA    = (u16*)  alloc((size_t)NN * HD * 2);     // bf16 buffers
    u16*   hB    = (u16*)  alloc((size_t)NN * HD * 2);

    k_build1 <<<NBLK + MM_BLOCKS, 256, 0, stream>>>(ei, hist, x, Wf, bf, hA);
    k_bscan  <<<NBUK, 64, 0, stream>>>(hist, btot);
    k_bstart <<<1, 64, 0, stream>>>(btot, bst, off);
    k_scatter<<<NBLK, 256, 0, stream>>>(ei, ew, hist, bst, recAB, recC);
    k_bucket <<<NBUK, 256, 0, stream>>>(recAB, recC, bst, dinv, off, csr);

    k_mm64 <<<MM_BLOCKS, 256, 0, stream>>>(hA, Wc1, dinv, hB);
    k_agg  <<<NN / 16, 256, 0, stream>>>((const u32*)hB, off, csr, dinv, bc1, (uint2*)hA);
    k_mm64 <<<MM_BLOCKS, 256, 0, stream>>>(hA, Wc2, dinv, hB);
    k_agg  <<<NN / 16, 256, 0, stream>>>((const u32*)hB, off, csr, dinv, bc2, (uint2*)hA);
    k_out  <<<MM_BLOCKS, 256, 0, stream>>>(hA, Wo, bo, out);
}